// Round 3
// baseline (2616.042 us; speedup 1.0000x reference)
//
#include <hip/hip_runtime.h>
#include <cmath>

#define B_SZ   512
#define L_SZ   196
#define DATT   2048
#define HATT   512
#define KCAT   3072
#define M_BIG  (B_SZ * L_SZ)   // 100352

typedef __attribute__((ext_vector_type(8))) short short8;   // 8 x bf16
typedef __attribute__((ext_vector_type(4))) float floatx4;  // MFMA acc
typedef unsigned short u16;
typedef unsigned int   u32;

__device__ __forceinline__ short8 as_s8(uint4 v) {
    union { uint4 u; short8 s; } c; c.u = v; return c.s;
}
__device__ __forceinline__ float bf2f(u16 u) {
    union { u32 i; float f; } v; v.i = ((u32)u) << 16; return v.f;
}
__device__ __forceinline__ u16 f2bf(float f) {
    union { float f; u32 i; } v; v.f = f;
    return (u16)((v.i + 0x7FFFu + ((v.i >> 16) & 1u)) >> 16);  // RNE
}
__device__ __forceinline__ float tanh_f(float x) {   // overflow-safe
    float a = __expf(2.0f * fabsf(x));
    float t = 1.0f - 2.0f / (1.0f + a);
    return (x < 0.0f) ? -t : t;
}
__device__ __forceinline__ float sigmoidf_(float x) {
    return 1.0f / (1.0f + __expf(-x));
}

// load 8 consecutive logical elements (index e, e%8==0) as canonical bf16x8
__device__ __forceinline__ uint4 ld8(const void* p, size_t e, int isbf) {
    if (isbf) return *(const uint4*)((const u16*)p + e);
    const float* f = (const float*)p + e;
    float4 lo = *(const float4*)f;
    float4 hi = *(const float4*)(f + 4);
    union { u16 o[8]; uint4 v; } u;
    u.o[0] = f2bf(lo.x); u.o[1] = f2bf(lo.y); u.o[2] = f2bf(lo.z); u.o[3] = f2bf(lo.w);
    u.o[4] = f2bf(hi.x); u.o[5] = f2bf(hi.y); u.o[6] = f2bf(hi.z); u.o[7] = f2bf(hi.w);
    return u.v;
}
__device__ __forceinline__ float ldf(const void* p, size_t e, int isbf) {
    return isbf ? bf2f(((const u16*)p)[e]) : ((const float*)p)[e];
}

// -------------------------------------------------------------- dtype detect
// Even-index u16s: bf16 data -> real bf16 values (exp 90..140 ~always);
// fp32 data -> low mantissa halves (uniform bits, ~20% in window).
__global__ void k_detect(const u16* __restrict__ af, int* __restrict__ flag) {
    __shared__ int cnt;
    if (threadIdx.x == 0) cnt = 0;
    __syncthreads();
    u16 u = af[(size_t)threadIdx.x * 2048];   // even index, in range both ways
    int e = (u >> 7) & 0xFF;
    if (e >= 90 && e <= 140) atomicAdd(&cnt, 1);
    __syncthreads();
    if (threadIdx.x == 0) *flag = (cnt >= 160) ? 1 : 0;
}

__global__ void k_init_scores(float* __restrict__ scores) {
    int i = blockIdx.x * 256 + threadIdx.x;
    if (i < M_BIG) scores[i] = 0.0f;
}

// -------------------- 128x128 MFMA GEMM, dual-dtype loaders, bf16 C output
// C[M,N] = A[M,K] @ Bcat[N,K]^T (+bias0+bias1 per n).  B: k<ksplit -> B1 else B2.
__global__ __launch_bounds__(256) void k_gemm(
    const int* __restrict__ flagp,
    const void* __restrict__ A, int lda, int a_always_bf,
    const void* __restrict__ B1, int ldb1, int ksplit,
    const void* __restrict__ B2, int ldb2,
    const void* __restrict__ bias0, const void* __restrict__ bias1,
    u16* __restrict__ C, int ldc, int K)
{
    const int isbf = *flagp;
    const int a_bf = a_always_bf | isbf;
    __shared__ uint4 As4[128 * 5];
    __shared__ uint4 Bs4[128 * 5];
    const int t = threadIdx.x;
    const int m0 = blockIdx.x * 128, n0 = blockIdx.y * 128;
    const int wid = t >> 6, lane = t & 63;
    const int cl = lane & 15, q = lane >> 4;
    const int mw = (wid & 1) * 64, nw = (wid >> 1) * 64;

    floatx4 acc[4][4];
    #pragma unroll
    for (int i = 0; i < 4; ++i)
        #pragma unroll
        for (int j = 0; j < 4; ++j) acc[i][j] = (floatx4){0.f, 0.f, 0.f, 0.f};

    for (int k0 = 0; k0 < K; k0 += 32) {
        #pragma unroll
        for (int i = 0; i < 2; ++i) {
            int c = t + i * 256, r = c >> 2, q4 = c & 3;
            As4[r * 5 + q4] = ld8(A, (size_t)(m0 + r) * lda + k0 + q4 * 8, a_bf);
        }
        #pragma unroll
        for (int i = 0; i < 2; ++i) {
            int c = t + i * 256, r = c >> 2, q4 = c & 3;
            int n = n0 + r;
            const void* src = (k0 < ksplit) ? B1 : B2;
            size_t off = (k0 < ksplit) ? ((size_t)n * ldb1 + k0 + q4 * 8)
                                       : ((size_t)n * ldb2 + (k0 - ksplit) + q4 * 8);
            Bs4[r * 5 + q4] = ld8(src, off, isbf);
        }
        __syncthreads();
        short8 a[4], b[4];
        #pragma unroll
        for (int mi = 0; mi < 4; ++mi)
            a[mi] = as_s8(As4[(mw + mi * 16 + cl) * 5 + q]);
        #pragma unroll
        for (int ni = 0; ni < 4; ++ni)
            b[ni] = as_s8(Bs4[(nw + ni * 16 + cl) * 5 + q]);
        #pragma unroll
        for (int mi = 0; mi < 4; ++mi)
            #pragma unroll
            for (int ni = 0; ni < 4; ++ni)
                acc[mi][ni] = __builtin_amdgcn_mfma_f32_16x16x32_bf16(
                    a[mi], b[ni], acc[mi][ni], 0, 0, 0);
        __syncthreads();
    }
    #pragma unroll
    for (int mi = 0; mi < 4; ++mi) {
        #pragma unroll
        for (int ni = 0; ni < 4; ++ni) {
            int gn = n0 + nw + ni * 16 + cl;
            float badd = 0.f;
            if (bias0) badd += ldf(bias0, gn, isbf);
            if (bias1) badd += ldf(bias1, gn, isbf);
            #pragma unroll
            for (int r = 0; r < 4; ++r) {
                int gm = m0 + mw + mi * 16 + q * 4 + r;
                C[(size_t)gm * ldc + gn] = f2bf(acc[mi][ni][r] + badd);
            }
        }
    }
}

// --------- fused score GEMM tile 128m x 128n + tanh·wa reduce -> atomicAdd
__global__ __launch_bounds__(256) void k_score(
    const int* __restrict__ flagp,
    const void* __restrict__ AF, const void* __restrict__ Wc,
    const u16* __restrict__ atth, const void* __restrict__ Wa,
    float* __restrict__ scores)
{
    const int isbf = *flagp;
    __shared__ uint4 As4[128 * 5];
    __shared__ uint4 Bs4[128 * 5];
    const int t = threadIdx.x;
    const int m0 = blockIdx.x * 128, n0 = blockIdx.y * 128;
    const int wid = t >> 6, lane = t & 63;
    const int cl = lane & 15, q = lane >> 4;
    const int mw = (wid & 1) * 64, nw = (wid >> 1) * 64;

    floatx4 acc[4][4];
    #pragma unroll
    for (int i = 0; i < 4; ++i)
        #pragma unroll
        for (int j = 0; j < 4; ++j) acc[i][j] = (floatx4){0.f, 0.f, 0.f, 0.f};

    for (int k0 = 0; k0 < DATT; k0 += 32) {
        #pragma unroll
        for (int i = 0; i < 2; ++i) {
            int c = t + i * 256, r = c >> 2, q4 = c & 3;
            As4[r * 5 + q4] = ld8(AF, (size_t)(m0 + r) * DATT + k0 + q4 * 8, isbf);
        }
        #pragma unroll
        for (int i = 0; i < 2; ++i) {
            int c = t + i * 256, r = c >> 2, q4 = c & 3;
            Bs4[r * 5 + q4] = ld8(Wc, (size_t)(n0 + r) * DATT + k0 + q4 * 8, isbf);
        }
        __syncthreads();
        short8 a[4], b[4];
        #pragma unroll
        for (int mi = 0; mi < 4; ++mi)
            a[mi] = as_s8(As4[(mw + mi * 16 + cl) * 5 + q]);
        #pragma unroll
        for (int ni = 0; ni < 4; ++ni)
            b[ni] = as_s8(Bs4[(nw + ni * 16 + cl) * 5 + q]);
        #pragma unroll
        for (int mi = 0; mi < 4; ++mi)
            #pragma unroll
            for (int ni = 0; ni < 4; ++ni)
                acc[mi][ni] = __builtin_amdgcn_mfma_f32_16x16x32_bf16(
                    a[mi], b[ni], acc[mi][ni], 0, 0, 0);
        __syncthreads();
    }
    float wa[4];
    #pragma unroll
    for (int ni = 0; ni < 4; ++ni)
        wa[ni] = ldf(Wa, n0 + nw + ni * 16 + cl, isbf);
    #pragma unroll
    for (int mi = 0; mi < 4; ++mi) {
        #pragma unroll
        for (int r = 0; r < 4; ++r) {
            int gm = m0 + mw + mi * 16 + q * 4 + r;
            int bidx = gm / L_SZ;
            float s = 0.f;
            #pragma unroll
            for (int ni = 0; ni < 4; ++ni) {
                int gn = n0 + nw + ni * 16 + cl;
                s += wa[ni] * tanh_f(acc[mi][ni][r] +
                                     bf2f(atth[(size_t)bidx * HATT + gn]));
            }
            s += __shfl_xor(s, 1);
            s += __shfl_xor(s, 2);
            s += __shfl_xor(s, 4);
            s += __shfl_xor(s, 8);
            if (cl == 0) atomicAdd(&scores[gm], s);
        }
    }
}

__global__ void k_softmax(float* __restrict__ sc) {
    int b = blockIdx.x, t = threadIdx.x;
    __shared__ float red[256];
    float v = (t < L_SZ) ? sc[b * L_SZ + t] : -1e30f;
    red[t] = v; __syncthreads();
    for (int s = 128; s > 0; s >>= 1) {
        if (t < s) red[t] = fmaxf(red[t], red[t + s]);
        __syncthreads();
    }
    float mx = red[0];
    __syncthreads();
    float e = (t < L_SZ) ? __expf(v - mx) : 0.f;
    red[t] = e; __syncthreads();
    for (int s = 128; s > 0; s >>= 1) {
        if (t < s) red[t] += red[t + s];
        __syncthreads();
    }
    float inv = 1.f / red[0];
    if (t < L_SZ) sc[b * L_SZ + t] = e * inv;
}

// ---------------- att_res + x_cat = [xt | att_res | h] (canonical bf16)
__global__ __launch_bounds__(256) void k_att_res(
    const int* __restrict__ flagp,
    const void* __restrict__ AF, const float* __restrict__ wts,
    const void* __restrict__ xt, const void* __restrict__ h,
    u16* __restrict__ x_cat)
{
    const int isbf = *flagp;
    int b = blockIdx.x, t = threadIdx.x;
    __shared__ float wsm[L_SZ];
    if (t < L_SZ) wsm[t] = wts[b * L_SZ + t];
    uint4* xc4 = (uint4*)(x_cat + (size_t)b * KCAT);
    if (t < 64) {
        xc4[t] = ld8(xt, (size_t)b * 512 + t * 8, isbf);
    } else if (t < 128) {
        xc4[320 + (t - 64)] = ld8(h, (size_t)b * 512 + (t - 64) * 8, isbf);
    }
    __syncthreads();
    float acc[8] = {0.f, 0.f, 0.f, 0.f, 0.f, 0.f, 0.f, 0.f};
    const size_t base = (size_t)b * L_SZ * DATT + t * 8;
    for (int l = 0; l < L_SZ; ++l) {
        uint4 raw = ld8(AF, base + (size_t)l * DATT, isbf);
        float w = wsm[l];
        const u16* p = (const u16*)&raw;
        #pragma unroll
        for (int j = 0; j < 8; ++j) acc[j] += w * bf2f(p[j]);
    }
    union { u16 o[8]; uint4 v; } u;
    #pragma unroll
    for (int j = 0; j < 8; ++j) u.o[j] = f2bf(acc[j]);
    xc4[64 + t] = u.v;
}

// -------------------------------------------------------- LSTM elementwise
__global__ void k_lstm(const int* __restrict__ flagp,
                       const u16* __restrict__ g,
                       const void* __restrict__ c_in,
                       void* __restrict__ out)
{
    const int isbf = *flagp;
    int idx = blockIdx.x * 256 + threadIdx.x;   // 262144 = B*512
    int b = idx >> 9, j = idx & 511;
    const u16* gb = g + (size_t)b * 2048;
    float ig = sigmoidf_(bf2f(gb[j]));
    float fg = sigmoidf_(bf2f(gb[512 + j]));
    float gg = tanh_f(bf2f(gb[1024 + j]));
    float og = sigmoidf_(bf2f(gb[1536 + j]));
    float cold = ldf(c_in, idx, isbf);
    float cn = fg * cold + ig * gg;
    float hn = og * tanh_f(cn);
    if (isbf) {
        u16* o = (u16*)out;
        u16 hb = f2bf(hn), cb = f2bf(cn);
        o[idx] = hb; o[262144 + idx] = hb; o[524288 + idx] = cb;
    } else {
        float* o = (float*)out;
        o[idx] = hn; o[262144 + idx] = hn; o[524288 + idx] = cn;
    }
}

extern "C" void kernel_launch(void* const* d_in, const int* in_sizes, int n_in,
                              void* d_out, int out_size, void* d_ws, size_t ws_size,
                              hipStream_t stream)
{
    const void* xt        = d_in[0];
    const void* att_feats = d_in[2];
    const void* h         = d_in[3];
    const void* c         = d_in[4];
    const void* W_ctx     = d_in[5];
    const void* b_ctx     = d_in[6];
    const void* W_h2att   = d_in[7];
    const void* b_h2att   = d_in[8];
    const void* W_alpha   = d_in[9];
    const void* W_ih      = d_in[11];
    const void* W_hh      = d_in[12];

    char* ws = (char*)d_ws;
    int*   flag   = (int*)ws;                              // @0
    u16*   atth   = (u16*)(ws + 256);                      // 512*512 bf16 = 512K
    float* scores = (float*)(ws + (1u << 20));             // 100352 f32 ~392K
    u16*   x_cat  = (u16*)(ws + (2u << 20));               // 512*3072 bf16 = 3M
    u16*   gates  = (u16*)(ws + (5u << 20));               // 512*2048 bf16 = 2M

    k_detect<<<dim3(1), dim3(256), 0, stream>>>((const u16*)att_feats, flag);
    k_init_scores<<<dim3(392), dim3(256), 0, stream>>>(scores);

    // atth = h @ W_h2att^T + b_ctx + b_h2att
    k_gemm<<<dim3(4, 4), dim3(256), 0, stream>>>(
        flag, h, 512, 0, W_h2att, 512, 512, W_h2att, 512,
        b_ctx, b_h2att, atth, 512, 512);

    k_score<<<dim3(M_BIG / 128, 4), dim3(256), 0, stream>>>(
        flag, att_feats, W_ctx, atth, W_alpha, scores);

    k_softmax<<<dim3(B_SZ), dim3(256), 0, stream>>>(scores);

    k_att_res<<<dim3(B_SZ), dim3(256), 0, stream>>>(
        flag, att_feats, scores, xt, h, x_cat);

    // gates = x_cat @ [W_ih | W_hh]^T   (A always canonical bf16)
    k_gemm<<<dim3(4, 16), dim3(256), 0, stream>>>(
        flag, x_cat, KCAT, 1, W_ih, 2560, 2560, W_hh, 512,
        (const void*)nullptr, (const void*)nullptr, gates, 2048, KCAT);

    k_lstm<<<dim3(1024), dim3(256), 0, stream>>>(flag, gates, c, d_out);
}